// Round 8
// baseline (2139.636 us; speedup 1.0000x reference)
//
#include <hip/hip_runtime.h>
#include <hip/hip_bf16.h>
#include <hip/hip_fp16.h>
#include <math.h>

#define NBLK 1008
#define NTHR 256
#define NT (NBLK * NTHR)

typedef _Float16 half8 __attribute__((ext_vector_type(8)));
typedef float f32x4 __attribute__((ext_vector_type(4)));

__device__ __forceinline__ float tanh_fast(float v) {
  // tanh(v) = 1 - 2/(exp(2v)+1); saturates correctly at +/-inf
  float e = __expf(v + v);
  return 1.0f - 2.0f * __builtin_amdgcn_rcpf(e + 1.0f);
}

// Grid barrier: monotonic counter in workspace (zeroed by memset each call).
// Release: __threadfence (agent: L2 writeback) + atomic add. Acquire: spin on
// agent-scope load, then __threadfence by ALL threads (L1/L2 invalidate) so
// cross-XCD writes are visible. Requires all NBLK blocks co-resident:
// 32KB LDS -> 5 blk/CU, launch_bounds(256,4) -> VGPR<=128 -> 4 blk/CU;
// NBLK=1008 <= 4*252 (4-CU margin).
__device__ __forceinline__ void gsync(unsigned* bar, unsigned target) {
  __syncthreads();
  if (threadIdx.x == 0) {
    __threadfence();
    __hip_atomic_fetch_add(bar, 1u, __ATOMIC_RELEASE,
                           __HIP_MEMORY_SCOPE_AGENT);
    while (__hip_atomic_load(bar, __ATOMIC_ACQUIRE,
                             __HIP_MEMORY_SCOPE_AGENT) < target)
      __builtin_amdgcn_s_sleep(1);
  }
  __syncthreads();
  __threadfence();
}

__device__ __forceinline__ float dot8h(float4 a, float4 b) {
  const __half2* pa = (const __half2*)&a;
  const __half2* pb = (const __half2*)&b;
  float s = 0.0f;
#pragma unroll
  for (int i = 0; i < 4; ++i) {
    float2 fa = __half22float2(pa[i]);
    float2 fb = __half22float2(pb[i]);
    s = fmaf(fa.x, fb.x, s);
    s = fmaf(fa.y, fb.y, s);
  }
  return s;
}

// ---------------------------------------------------------------------------
// Single resident kernel; phases separated by gsync. Work mapping per phase
// identical to the round-7 multi-kernel version (numerics unchanged).
// ---------------------------------------------------------------------------
__global__ __launch_bounds__(NTHR, 4) void k_mega(
    const float* __restrict__ x, const float* __restrict__ mask,
    const int* __restrict__ rows, const int* __restrict__ cols,
    const float* __restrict__ W, const float* __restrict__ bl,
    const float* __restrict__ alpha_p, const float* __restrict__ bias_p,
    __half* __restrict__ hn, int* __restrict__ cnt, int* __restrict__ off,
    int* __restrict__ cursor, int* __restrict__ bsum,
    unsigned* __restrict__ rec, int* __restrict__ perm,
    float* __restrict__ csr_w, unsigned short* __restrict__ src16,
    float* __restrict__ h0, float* __restrict__ f_a, float* __restrict__ f_b,
    float* __restrict__ rsd, float* __restrict__ fill, float* __restrict__ ew,
    unsigned* __restrict__ bar, int N, int E) {
  __shared__ _Float16 wsh[128 * 128];  // 32 KB: W tile (P0), scan scratch later
  const int tid = threadIdx.x;
  const int bid = blockIdx.x;
  const int tg = bid * NTHR + tid;
  unsigned tgt = 0;

  // ======== P0: W->LDS (swizzled), GEMM tile, node inits, col histogram ====
  for (int i = tid; i < 2048; i += NTHR) {
    int row = i >> 4, cc = i & 15;
    const float4* wr = (const float4*)(W + row * 128 + cc * 8);
    float4 a = wr[0], b = wr[1];
    half8 h;
    h[0] = (_Float16)a.x; h[1] = (_Float16)a.y;
    h[2] = (_Float16)a.z; h[3] = (_Float16)a.w;
    h[4] = (_Float16)b.x; h[5] = (_Float16)b.y;
    h[6] = (_Float16)b.z; h[7] = (_Float16)b.w;
    *(half8*)((char*)wsh + row * 256 + ((cc * 16) ^ ((row & 7) << 4))) = h;
  }
  __syncthreads();

  {
    const int wv = tid >> 6, lane = tid & 63;
    const int NTILES = (N + 63) / 64;  // 782 <= NBLK: one tile per block
    if (bid < NTILES) {
      const int row0 = bid * 64 + wv * 16;
      if (row0 < N) {
        const int r = lane & 15;  // A-row / C-col
        const int g = lane >> 4;  // k-group / C-row-group
        half8 afrag[4];
        {
          const float4* xr = (const float4*)(x + (size_t)(row0 + r) * 128);
#pragma unroll
          for (int ks = 0; ks < 4; ++ks) {
            float4 lo = xr[ks * 8 + g * 2];
            float4 hi = xr[ks * 8 + g * 2 + 1];
            half8 a;
            a[0] = (_Float16)lo.x; a[1] = (_Float16)lo.y;
            a[2] = (_Float16)lo.z; a[3] = (_Float16)lo.w;
            a[4] = (_Float16)hi.x; a[5] = (_Float16)hi.y;
            a[6] = (_Float16)hi.z; a[7] = (_Float16)hi.w;
            afrag[ks] = a;
          }
        }
        f32x4 acc[8];
#pragma unroll
        for (int c = 0; c < 8; ++c) acc[c] = (f32x4){0.f, 0.f, 0.f, 0.f};
#pragma unroll
        for (int c = 0; c < 8; ++c) {
          const char* base = (const char*)wsh + (c * 16 + r) * 256;
          const int sw = ((c * 16 + r) & 7) << 4;
#pragma unroll
          for (int ks = 0; ks < 4; ++ks) {
            half8 b = *(const half8*)(base + ((ks * 64 + g * 16) ^ sw));
            acc[c] = __builtin_amdgcn_mfma_f32_16x16x32_f16(afrag[ks], b,
                                                            acc[c], 0, 0, 0);
          }
        }
        float t[8][4];
        float ss[4] = {0.f, 0.f, 0.f, 0.f};
#pragma unroll
        for (int c = 0; c < 8; ++c) {
          float bv = bl[c * 16 + r];
#pragma unroll
          for (int j = 0; j < 4; ++j) {
            float tv = tanh_fast(acc[c][j] + bv);
            t[c][j] = tv;
            ss[j] = fmaf(tv, tv, ss[j]);
          }
        }
#pragma unroll
        for (int j = 0; j < 4; ++j) {
#pragma unroll
          for (int o = 8; o; o >>= 1) ss[j] += __shfl_xor(ss[j], o);
          ss[j] = 1.0f / fmaxf(sqrtf(ss[j]), 1e-8f);
        }
#pragma unroll
        for (int c = 0; c < 8; ++c)
#pragma unroll
          for (int j = 0; j < 4; ++j)
            hn[(size_t)(row0 + g * 4 + j) * 128 + c * 16 + r] =
                __float2half_rn(t[c][j] * ss[j]);
      }
    }
  }
  for (int i = tg; i < N; i += NT) {
    float v = fmaxf(mask[i], 0.0f);
    h0[i] = v;
    f_a[i] = v;
  }
  for (int e = tg; e < E; e += NT) atomicAdd(cnt + cols[e], 1);
  tgt += NBLK; gsync(bar, tgt);

  // ======== P1: per-chunk block sums of cnt =================================
  const int NCH = (N + 255) / 256;  // 196 <= 256 and <= NBLK
  {
    int* si = (int*)wsh;
    if (bid < NCH) {
      int i = bid * 256 + tid;
      si[tid] = (i < N) ? cnt[i] : 0;
      __syncthreads();
      for (int d = 128; d; d >>= 1) {
        if (tid < d) si[tid] += si[tid + d];
        __syncthreads();
      }
      if (tid == 0) bsum[bid] = si[0];
    }
  }
  tgt += NBLK; gsync(bar, tgt);

  // ======== P2: exclusive scan -> off, cursor (each block scans bsum) =======
  {
    if (bid < NCH) {
      int* bscan = (int*)wsh;         // [2][256]
      int* cscan = (int*)wsh + 1024;  // [2][256]
      int bv = (tid < NCH) ? bsum[tid] : 0;
      bscan[tid] = bv;
      __syncthreads();
      int a = 0;
      for (int d = 1; d < 256; d <<= 1) {
        int v2 = bscan[a * 256 + tid];
        if (tid >= d) v2 += bscan[a * 256 + tid - d];
        bscan[(a ^ 1) * 256 + tid] = v2;
        __syncthreads();
        a ^= 1;
      }
      int bpre = (bid > 0) ? bscan[a * 256 + bid - 1] : 0;
      int i = bid * 256 + tid;
      int v = (i < N) ? cnt[i] : 0;
      cscan[tid] = v;
      __syncthreads();
      int b2 = 0;
      for (int d = 1; d < 256; d <<= 1) {
        int v2 = cscan[b2 * 256 + tid];
        if (tid >= d) v2 += cscan[b2 * 256 + tid - d];
        cscan[(b2 ^ 1) * 256 + tid] = v2;
        __syncthreads();
        b2 ^= 1;
      }
      int excl = cscan[b2 * 256 + tid] - v + bpre;
      if (i < N) {
        off[i] = excl;
        cursor[i] = excl;
      }
      if (bid == 0 && tid == 0) off[N] = E;
    }
  }
  tgt += NBLK; gsync(bar, tgt);

  // ======== P3: build col-sorted records + inverse permutation ==============
  for (int e = tg; e < E; e += NT) {
    unsigned r = (unsigned)rows[e], c = (unsigned)cols[e];
    int pos = atomicAdd(cursor + c, 1);
    rec[pos] = r | (c << 16);
    perm[e] = pos;
  }
  tgt += NBLK; gsync(bar, tgt);

  // ======== P4: edge cosine (4 lanes/edge, col-sorted, sequential writes) ===
  {
    const int sub = tg & 3;
    for (int pos = tg >> 2; pos < E; pos += (NT >> 2)) {
      unsigned rc = rec[pos];
      unsigned row = rc & 0xffffu, col = rc >> 16;
      const float4* hr = (const float4*)(hn + (size_t)row * 128);
      const float4* hc = (const float4*)(hn + (size_t)col * 128);
      float4 a0 = hr[sub], a1 = hr[sub + 4], a2 = hr[sub + 8],
             a3 = hr[sub + 12];
      float4 b0 = hc[sub], b1 = hc[sub + 4], b2 = hc[sub + 8],
             b3 = hc[sub + 12];
      float dot =
          dot8h(a0, b0) + dot8h(a1, b1) + dot8h(a2, b2) + dot8h(a3, b3);
      dot += __shfl_xor(dot, 1);
      dot += __shfl_xor(dot, 2);
      if (sub == 0) {
        csr_w[pos] = fmaxf(dot, 0.0f);
        src16[pos] = (unsigned short)row;
      }
    }
  }
  tgt += NBLK; gsync(bar, tgt);

  // ======== P5: un-permute ew (d_out) + segmented degree -> rsd =============
  for (int e = tg; e < E; e += NT) ew[e] = csr_w[perm[e]];
  {
    const int sub = tg & 3;
    for (int n = tg >> 2; n < N; n += (NT >> 2)) {
      int s0 = off[n], s1 = off[n + 1];
      float s = 0.0f;
      for (int i = s0 + sub; i < s1; i += 4) s += csr_w[i];
      s += __shfl_xor(s, 1);
      s += __shfl_xor(s, 2);
      if (sub == 0) rsd[n] = rsqrtf(1.0f + s);  // self-loop weight 1
    }
  }
  tgt += NBLK; gsync(bar, tgt);

  // ======== P6..P10: K=5 APPNP iterations (iter 0 normalizes csr_w) =========
  const float aval = alpha_p[0];
  const int sub = tg & 3;
  for (int it = 0; it < 5; ++it) {
    const float* fi = (it & 1) ? f_b : f_a;
    float* fo = (it & 1) ? f_a : f_b;
    for (int n = tg >> 2; n < N; n += (NT >> 2)) {
      float rs_n = rsd[n];
      int s0 = off[n], s1 = off[n + 1];
      float part = 0.0f;
      if (it == 0) {
        for (int i = s0 + sub; i < s1; i += 4) {
          int s = src16[i];
          float wn = csr_w[i] * rs_n * rsd[s];
          csr_w[i] = wn;  // i unique to this node's lanes
          part = fmaf(wn, fi[s], part);
        }
      } else {
        for (int i = s0 + sub; i < s1; i += 4)
          part = fmaf(csr_w[i], fi[src16[i]], part);
      }
      part += __shfl_xor(part, 1);
      part += __shfl_xor(part, 2);
      if (sub == 0) {
        float agg = part + fi[n] * rs_n * rs_n;  // self-loop: norm = 1/deg
        float fn = (1.0f - aval) * agg + aval * h0[n];
        if (it == 4) {
          float b = bias_p[0];
          float sp = (b > 20.0f) ? b : log1pf(expf(b));
          fill[n] = tanhf(fn - sp);
        } else {
          fo[n] = fn;
        }
      }
    }
    if (it < 4) {
      tgt += NBLK;
      gsync(bar, tgt);
    }
  }
}

// ---------------------------------------------------------------------------
extern "C" void kernel_launch(void* const* d_in, const int* in_sizes, int n_in,
                              void* d_out, int out_size, void* d_ws,
                              size_t ws_size, hipStream_t stream) {
  const float* x = (const float*)d_in[0];
  const float* mask = (const float*)d_in[1];
  const int* ei = (const int*)d_in[2];  // [2, E] int32 (jax x64 disabled)
  const float* W = (const float*)d_in[3];
  const float* bl = (const float*)d_in[4];
  const float* alpha = (const float*)d_in[5];
  const float* bias = (const float*)d_in[6];

  const int D = 128;
  const int N = in_sizes[0] / D;  // 50000  (< 65536: u16 node ids)
  const int E = in_sizes[2] / 2;  // 600000
  const int* rows = ei;
  const int* cols = ei + E;

  float* fill = (float*)d_out;    // [N]
  float* ew = (float*)d_out + N;  // [E] edge_weights output slice

  // workspace carve-up (256B aligned)
  char* w = (char*)d_ws;
  size_t off_b = 0;
  auto alloc = [&](size_t bytes) -> void* {
    void* p = (void*)(w + off_b);
    off_b = (off_b + bytes + 255) & ~(size_t)255;
    return p;
  };
  __half* hn = (__half*)alloc((size_t)N * D * sizeof(__half));  // 12.8 MB
  // cnt + bar share one zeroing memset (adjacent allocs)
  size_t zero_base = off_b;
  int* cnt = (int*)alloc((size_t)N * sizeof(int));
  unsigned* bar = (unsigned*)alloc(256);
  size_t zero_len = off_b - zero_base;
  int* off = (int*)alloc((size_t)(N + 1) * sizeof(int));
  int* cursor = (int*)alloc((size_t)N * sizeof(int));
  int* bsum = (int*)alloc(256 * sizeof(int));
  unsigned* rec = (unsigned*)alloc((size_t)E * sizeof(unsigned));  // 2.4 MB
  int* perm = (int*)alloc((size_t)E * sizeof(int));                // 2.4 MB
  float* csr_w = (float*)alloc((size_t)E * sizeof(float));         // 2.4 MB
  unsigned short* src16 =
      (unsigned short*)alloc((size_t)E * sizeof(unsigned short));
  float* h0 = (float*)alloc((size_t)N * sizeof(float));
  float* f_a = (float*)alloc((size_t)N * sizeof(float));
  float* f_b = (float*)alloc((size_t)N * sizeof(float));
  float* rsd = (float*)alloc((size_t)N * sizeof(float));
  (void)ws_size;

  hipMemsetAsync((char*)d_ws + zero_base, 0, zero_len, stream);
  k_mega<<<NBLK, NTHR, 0, stream>>>(x, mask, rows, cols, W, bl, alpha, bias,
                                    hn, cnt, off, cursor, bsum, rec, perm,
                                    csr_w, src16, h0, f_a, f_b, rsd, fill, ew,
                                    bar, N, E);
}

// Round 9
// 143.250 us; speedup vs baseline: 14.9363x; 14.9363x over previous
//
#include <hip/hip_runtime.h>
#include <hip/hip_bf16.h>
#include <hip/hip_fp16.h>
#include <math.h>

typedef _Float16 half8 __attribute__((ext_vector_type(8)));
typedef float f32x4 __attribute__((ext_vector_type(4)));

__device__ __forceinline__ float tanh_fast(float v) {
  // tanh(v) = 1 - 2/(exp(2v)+1); saturates correctly at +/-inf
  float e = __expf(v + v);
  return 1.0f - 2.0f * __builtin_amdgcn_rcpf(e + 1.0f);
}

__device__ __forceinline__ float dot8h(float4 a, float4 b) {
  const __half2* pa = (const __half2*)&a;
  const __half2* pb = (const __half2*)&b;
  float s = 0.0f;
#pragma unroll
  for (int i = 0; i < 4; ++i) {
    float2 fa = __half22float2(pa[i]);
    float2 fb = __half22float2(pb[i]);
    s = fmaf(fa.x, fb.x, s);
    s = fmaf(fa.y, fb.y, s);
  }
  return s;
}

// ---------------------------------------------------------------------------
// Front kernel: (a) bid < NTILES: MFMA GEMM tile -> tanh -> normalize -> fp16
// hn (W staged fp32->f16 in 32KB XOR-swizzled LDS, byte ^= (row&7)<<4, so
// ds_read_b128 is conflict-free); (b) all blocks: grid-stride node inits
// (h0, f_a) + col histogram. Histogram atomics overlap the GEMM's MFMA/LDS
// phases. C mapping: col=l&15, row=(l>>4)*4+reg [m89/m91].
// ---------------------------------------------------------------------------
__global__ __launch_bounds__(256) void k_front(
    const float* __restrict__ x, const float* __restrict__ W,
    const float* __restrict__ bl, const float* __restrict__ mask,
    const int* __restrict__ cols, __half* __restrict__ hn,
    int* __restrict__ cnt, float* __restrict__ h0, float* __restrict__ f_a,
    int N, int E, int nblk) {
  __shared__ _Float16 wsh[128 * 128];  // 32 KB, swizzled
  const int tid = threadIdx.x;
  const int bid = blockIdx.x;
  const int NTILES = (N + 63) / 64;

  if (bid < NTILES) {  // block-uniform branch: __syncthreads inside is legal
    for (int i = tid; i < 2048; i += 256) {
      int row = i >> 4, cc = i & 15;
      const float4* wr = (const float4*)(W + row * 128 + cc * 8);
      float4 a = wr[0], b = wr[1];
      half8 h;
      h[0] = (_Float16)a.x; h[1] = (_Float16)a.y;
      h[2] = (_Float16)a.z; h[3] = (_Float16)a.w;
      h[4] = (_Float16)b.x; h[5] = (_Float16)b.y;
      h[6] = (_Float16)b.z; h[7] = (_Float16)b.w;
      *(half8*)((char*)wsh + row * 256 + ((cc * 16) ^ ((row & 7) << 4))) = h;
    }
    __syncthreads();

    const int wv = tid >> 6, lane = tid & 63;
    const int row0 = bid * 64 + wv * 16;
    if (row0 < N) {  // wave-granular tail guard (N % 16 == 0)
      const int r = lane & 15;  // A-row / C-col
      const int g = lane >> 4;  // k-group / C-row-group
      half8 afrag[4];
      {
        const float4* xr = (const float4*)(x + (size_t)(row0 + r) * 128);
#pragma unroll
        for (int ks = 0; ks < 4; ++ks) {
          float4 lo = xr[ks * 8 + g * 2];
          float4 hi = xr[ks * 8 + g * 2 + 1];
          half8 a;
          a[0] = (_Float16)lo.x; a[1] = (_Float16)lo.y;
          a[2] = (_Float16)lo.z; a[3] = (_Float16)lo.w;
          a[4] = (_Float16)hi.x; a[5] = (_Float16)hi.y;
          a[6] = (_Float16)hi.z; a[7] = (_Float16)hi.w;
          afrag[ks] = a;
        }
      }
      f32x4 acc[8];
#pragma unroll
      for (int c = 0; c < 8; ++c) acc[c] = (f32x4){0.f, 0.f, 0.f, 0.f};
#pragma unroll
      for (int c = 0; c < 8; ++c) {
        const char* base = (const char*)wsh + (c * 16 + r) * 256;
        const int sw = ((c * 16 + r) & 7) << 4;
#pragma unroll
        for (int ks = 0; ks < 4; ++ks) {
          half8 b = *(const half8*)(base + ((ks * 64 + g * 16) ^ sw));
          acc[c] = __builtin_amdgcn_mfma_f32_16x16x32_f16(afrag[ks], b,
                                                          acc[c], 0, 0, 0);
        }
      }
      float t[8][4];
      float ss[4] = {0.f, 0.f, 0.f, 0.f};
#pragma unroll
      for (int c = 0; c < 8; ++c) {
        float bv = bl[c * 16 + r];
#pragma unroll
        for (int j = 0; j < 4; ++j) {
          float tv = tanh_fast(acc[c][j] + bv);
          t[c][j] = tv;
          ss[j] = fmaf(tv, tv, ss[j]);
        }
      }
#pragma unroll
      for (int j = 0; j < 4; ++j) {
#pragma unroll
        for (int o = 8; o; o >>= 1) ss[j] += __shfl_xor(ss[j], o);
        ss[j] = 1.0f / fmaxf(sqrtf(ss[j]), 1e-8f);
      }
#pragma unroll
      for (int c = 0; c < 8; ++c)
#pragma unroll
        for (int j = 0; j < 4; ++j)
          hn[(size_t)(row0 + g * 4 + j) * 128 + c * 16 + r] =
              __float2half_rn(t[c][j] * ss[j]);
    }
  }

  // grid-stride node inits + col histogram (all blocks)
  const int tg = bid * 256 + tid;
  const int NT = nblk * 256;
  for (int i = tg; i < N; i += NT) {
    float v = fmaxf(mask[i], 0.0f);
    h0[i] = v;
    f_a[i] = v;
  }
  for (int e = tg; e < E; e += NT) atomicAdd(cnt + cols[e], 1);
}

// ---------------------------------------------------------------------------
// Scan step 1: per-256-chunk block sums of cnt.
// ---------------------------------------------------------------------------
__global__ __launch_bounds__(256) void k_scan_a(const int* __restrict__ cnt,
                                                int* __restrict__ bsum,
                                                int N) {
  __shared__ int s[256];
  int i = blockIdx.x * 256 + threadIdx.x;
  s[threadIdx.x] = (i < N) ? cnt[i] : 0;
  __syncthreads();
  for (int d = 128; d; d >>= 1) {
    if (threadIdx.x < d) s[threadIdx.x] += s[threadIdx.x + d];
    __syncthreads();
  }
  if (threadIdx.x == 0) bsum[blockIdx.x] = s[0];
}

// ---------------------------------------------------------------------------
// Scan step 2 (folds old scan_b + scan_c): each block redundantly scans the
// <=256 block sums in LDS, then scans its own 256-chunk of cnt -> off,cursor.
// ---------------------------------------------------------------------------
__global__ __launch_bounds__(256) void k_scan_bc(
    const int* __restrict__ cnt, const int* __restrict__ bsum,
    int* __restrict__ off, int* __restrict__ cursor, int N, int E, int NCH) {
  __shared__ int bscan[2 * 256];
  __shared__ int cscan[2 * 256];
  const int t = threadIdx.x, bid = blockIdx.x;
  int bv = (t < NCH) ? bsum[t] : 0;
  bscan[t] = bv;
  __syncthreads();
  int a = 0;
  for (int d = 1; d < 256; d <<= 1) {
    int v2 = bscan[a * 256 + t];
    if (t >= d) v2 += bscan[a * 256 + t - d];
    bscan[(a ^ 1) * 256 + t] = v2;
    __syncthreads();
    a ^= 1;
  }
  int bpre = (bid > 0) ? bscan[a * 256 + bid - 1] : 0;  // exclusive prefix
  int i = bid * 256 + t;
  int v = (i < N) ? cnt[i] : 0;
  cscan[t] = v;
  __syncthreads();
  int b2 = 0;
  for (int d = 1; d < 256; d <<= 1) {
    int v2 = cscan[b2 * 256 + t];
    if (t >= d) v2 += cscan[b2 * 256 + t - d];
    cscan[(b2 ^ 1) * 256 + t] = v2;
    __syncthreads();
    b2 ^= 1;
  }
  int excl = cscan[b2 * 256 + t] - v + bpre;
  if (i < N) {
    off[i] = excl;
    cursor[i] = excl;
  }
  if (i == 0) off[N] = E;
}

// rec[pos] = row | col<<16 (u32); perm[e] = pos (for the ew un-permute).
__global__ void k_build(const int* __restrict__ rows,
                        const int* __restrict__ cols, int* __restrict__ cursor,
                        unsigned* __restrict__ rec, int* __restrict__ perm,
                        int E) {
  int e = blockIdx.x * 256 + threadIdx.x;
  if (e >= E) return;
  unsigned r = (unsigned)rows[e], c = (unsigned)cols[e];
  int pos = atomicAdd(cursor + c, 1);
  rec[pos] = r | (c << 16);
  perm[e] = pos;
}

// ---------------------------------------------------------------------------
// Edge cosine, col-sorted, 4 lanes/edge x 2 edges per quad (p and p+Q).
// All 8 random row-loads issued first (double queue depth vs 1-edge version);
// col loads (L1/L2-hot) follow. Sequential writes only.
// ---------------------------------------------------------------------------
__global__ __launch_bounds__(256) void k_edge_cos(
    const __half* __restrict__ hn, const unsigned* __restrict__ rec,
    float* __restrict__ csr_w, unsigned short* __restrict__ src16, int E,
    int Q) {
  int t = blockIdx.x * 256 + threadIdx.x;
  int q = t >> 2, sub = t & 3;
  if (q >= Q) return;
  const int p0 = q, p1 = q + Q;
  const bool has1 = p1 < E;
  unsigned rc0 = rec[p0];
  unsigned rc1 = has1 ? rec[p1] : rc0;
  const float4* hr0 = (const float4*)(hn + (size_t)(rc0 & 0xffffu) * 128);
  const float4* hr1 = (const float4*)(hn + (size_t)(rc1 & 0xffffu) * 128);
  // 8 random row loads in flight
  float4 r00 = hr0[sub], r01 = hr0[sub + 4], r02 = hr0[sub + 8],
         r03 = hr0[sub + 12];
  float4 r10 = hr1[sub], r11 = hr1[sub + 4], r12 = hr1[sub + 8],
         r13 = hr1[sub + 12];
  const float4* hc0 = (const float4*)(hn + (size_t)(rc0 >> 16) * 128);
  const float4* hc1 = (const float4*)(hn + (size_t)(rc1 >> 16) * 128);
  float d0 = dot8h(r00, hc0[sub]) + dot8h(r01, hc0[sub + 4]) +
             dot8h(r02, hc0[sub + 8]) + dot8h(r03, hc0[sub + 12]);
  float d1 = dot8h(r10, hc1[sub]) + dot8h(r11, hc1[sub + 4]) +
             dot8h(r12, hc1[sub + 8]) + dot8h(r13, hc1[sub + 12]);
  d0 += __shfl_xor(d0, 1);
  d0 += __shfl_xor(d0, 2);
  d1 += __shfl_xor(d1, 1);
  d1 += __shfl_xor(d1, 2);
  if (sub == 0) {
    csr_w[p0] = fmaxf(d0, 0.0f);
    src16[p0] = (unsigned short)(rc0 & 0xffffu);
    if (has1) {
      csr_w[p1] = fmaxf(d1, 0.0f);
      src16[p1] = (unsigned short)(rc1 & 0xffffu);
    }
  }
}

// ---------------------------------------------------------------------------
// Fused: (a) un-permute raw weights to ew[e] (sequential write, random read
// of L2-resident csr_w); (b) deterministic segmented degree sum -> rsd.
// ---------------------------------------------------------------------------
__global__ __launch_bounds__(256) void k_unperm_rsd(
    const float* __restrict__ csr_w, const int* __restrict__ perm,
    const int* __restrict__ off, float* __restrict__ ew,
    float* __restrict__ rsd, int N, int E) {
  int t = blockIdx.x * 256 + threadIdx.x;
  if (t < E) ew[t] = csr_w[perm[t]];
  int n = t >> 2, sub = t & 3;
  if (n < N) {
    int s0 = off[n], s1 = off[n + 1];
    float s = 0.0f;
    for (int i = s0 + sub; i < s1; i += 4) s += csr_w[i];
    s += __shfl_xor(s, 1);
    s += __shfl_xor(s, 2);
    if (sub == 0) rsd[n] = rsqrtf(1.0f + s);  // self-loop weight 1
  }
}

// ---------------------------------------------------------------------------
// One APPNP iteration, fused gather-reduce + update. 4 lanes per node.
// mode bit0: first iter, normalize csr_w in place (wn = raw*rsd[src]*rsd[n]).
// mode bit1: last iter, write fill = tanh(f - softplus(bias)) to d_out.
// ---------------------------------------------------------------------------
__global__ __launch_bounds__(256) void k_prop(
    const float* __restrict__ f_in, float* __restrict__ f_out,
    float* __restrict__ csr_w, const unsigned short* __restrict__ src16,
    const int* __restrict__ off, const float* __restrict__ h0,
    const float* __restrict__ rsd, const float* __restrict__ alpha_p,
    const float* __restrict__ bias_p, float* __restrict__ fill, int N,
    int mode) {
  int t = blockIdx.x * 256 + threadIdx.x;
  int n = t >> 2, sub = t & 3;
  if (n >= N) return;
  float rs_n = rsd[n];
  int s0 = off[n], s1 = off[n + 1];
  float part = 0.0f;
  if (mode & 1) {
    for (int i = s0 + sub; i < s1; i += 4) {
      int s = src16[i];
      float wn = csr_w[i] * rs_n * rsd[s];
      csr_w[i] = wn;  // segment owned by this node's 4 lanes; i unique
      part = fmaf(wn, f_in[s], part);
    }
  } else {
    for (int i = s0 + sub; i < s1; i += 4)
      part = fmaf(csr_w[i], f_in[src16[i]], part);
  }
  part += __shfl_xor(part, 1);
  part += __shfl_xor(part, 2);
  if (sub == 0) {
    float a = alpha_p[0];
    float agg = part + f_in[n] * rs_n * rs_n;  // self-loop: norm = 1/deg
    float fn = (1.0f - a) * agg + a * h0[n];
    if (mode & 2) {
      float b = bias_p[0];
      float sp = (b > 20.0f) ? b : log1pf(expf(b));
      fill[n] = tanhf(fn - sp);
    } else {
      f_out[n] = fn;
    }
  }
}

// ---------------------------------------------------------------------------
extern "C" void kernel_launch(void* const* d_in, const int* in_sizes, int n_in,
                              void* d_out, int out_size, void* d_ws,
                              size_t ws_size, hipStream_t stream) {
  const float* x = (const float*)d_in[0];
  const float* mask = (const float*)d_in[1];
  const int* ei = (const int*)d_in[2];  // [2, E] int32 (jax x64 disabled)
  const float* W = (const float*)d_in[3];
  const float* bl = (const float*)d_in[4];
  const float* alpha = (const float*)d_in[5];
  const float* bias = (const float*)d_in[6];

  const int D = 128;
  const int N = in_sizes[0] / D;  // 50000  (< 65536: u16 node ids)
  const int E = in_sizes[2] / 2;  // 600000
  const int* rows = ei;
  const int* cols = ei + E;

  float* fill = (float*)d_out;    // [N]
  float* ew = (float*)d_out + N;  // [E] edge_weights output slice

  // workspace carve-up (256B aligned)
  char* w = (char*)d_ws;
  size_t off_b = 0;
  auto alloc = [&](size_t bytes) -> void* {
    void* p = (void*)(w + off_b);
    off_b = (off_b + bytes + 255) & ~(size_t)255;
    return p;
  };
  __half* hn = (__half*)alloc((size_t)N * D * sizeof(__half));  // 12.8 MB
  int* cnt = (int*)alloc((size_t)N * sizeof(int));
  int* off = (int*)alloc((size_t)(N + 1) * sizeof(int));
  int* cursor = (int*)alloc((size_t)N * sizeof(int));
  int* bsum = (int*)alloc(256 * sizeof(int));
  unsigned* rec = (unsigned*)alloc((size_t)E * sizeof(unsigned));  // 2.4 MB
  int* perm = (int*)alloc((size_t)E * sizeof(int));                // 2.4 MB
  float* csr_w = (float*)alloc((size_t)E * sizeof(float));         // 2.4 MB
  unsigned short* src16 =
      (unsigned short*)alloc((size_t)E * sizeof(unsigned short));
  float* h0 = (float*)alloc((size_t)N * sizeof(float));
  float* f_a = (float*)alloc((size_t)N * sizeof(float));
  float* f_b = (float*)alloc((size_t)N * sizeof(float));
  float* rsd = (float*)alloc((size_t)N * sizeof(float));
  (void)ws_size;

  const int NCH = (N + 255) / 256;  // 196 <= 256 (scan capacity)
  const int nb_E = (E + 255) / 256;
  const int FRONT_BLOCKS = 1024;  // >= NTILES (782)

  hipMemsetAsync(cnt, 0, (size_t)N * sizeof(int), stream);
  // GEMM + tanh + normalize + fp16 store, fused node inits + col histogram
  k_front<<<FRONT_BLOCKS, 256, 0, stream>>>(x, W, bl, mask, cols, hn, cnt, h0,
                                            f_a, N, E, FRONT_BLOCKS);
  // exclusive scan of cnt -> off, cursor (2 dispatches)
  k_scan_a<<<NCH, 256, 0, stream>>>(cnt, bsum, N);
  k_scan_bc<<<NCH, 256, 0, stream>>>(cnt, bsum, off, cursor, N, E, NCH);
  // col-sorted edge records + inverse permutation
  k_build<<<nb_E, 256, 0, stream>>>(rows, cols, cursor, rec, perm, E);
  // cosine in sorted order -> csr_w + src16 (2 edges per lane-quad)
  const int Q = (E + 1) / 2;
  k_edge_cos<<<(Q * 4 + 255) / 256, 256, 0, stream>>>(hn, rec, csr_w, src16,
                                                      E, Q);
  // un-permute raw weights to ew (d_out) + segmented degree -> rsd
  k_unperm_rsd<<<nb_E, 256, 0, stream>>>(csr_w, perm, off, ew, rsd, N, E);
  // K=5 APPNP iterations (gather-reduce; iter 0 normalizes csr_w in place)
  const float* fi = f_a;
  float* fo = f_b;
  for (int it = 0; it < 5; ++it) {
    int mode = (it == 0 ? 1 : 0) | (it == 4 ? 2 : 0);
    k_prop<<<(N * 4 + 255) / 256, 256, 0, stream>>>(
        fi, fo, csr_w, src16, off, h0, rsd, alpha, bias, fill, N, mode);
    const float* tmp = fo;
    fo = (float*)fi;
    fi = tmp;
  }
}